// Round 9
// baseline (192.876 us; speedup 1.0000x reference)
//
#include <hip/hip_runtime.h>
#include <math.h>

// Problem constants: B=2, D=512, N=M=2048, H=8, K=V=64
#define BB 2
#define DDIM 512
#define NSEQ 2048
#define NHEAD 8

typedef __attribute__((ext_vector_type(4))) short s16x4;
typedef __attribute__((ext_vector_type(8))) short s16x8;
typedef __attribute__((ext_vector_type(4))) float f32x4;

__device__ __forceinline__ unsigned short f2bf(float f) {
    unsigned u = __float_as_uint(f);
    u = (u + 0x7FFFu + ((u >> 16) & 1u)) >> 16;   // RNE
    return (unsigned short)u;
}
__device__ __forceinline__ float bf2f(unsigned short h) {
    return __uint_as_float(((unsigned)h) << 16);
}
__device__ __forceinline__ s16x4 pack4(float a, float b, float c, float d) {
    s16x4 r;
    r[0] = (short)f2bf(a); r[1] = (short)f2bf(b);
    r[2] = (short)f2bf(c); r[3] = (short)f2bf(d);
    return r;
}

__device__ __forceinline__ f32x4 mfma32(s16x8 a, s16x8 b, f32x4 c) {
    return __builtin_amdgcn_mfma_f32_16x16x32_bf16(a, b, c, 0, 0, 0);
}
__device__ __forceinline__ f32x4 mfma16(s16x4 a, s16x4 b, f32x4 c) {
#if __has_builtin(__builtin_amdgcn_mfma_f32_16x16x16bf16_1k)
    return __builtin_amdgcn_mfma_f32_16x16x16bf16_1k(a, b, c, 0, 0, 0);
#else
    s16x8 a8 = { a[0], a[1], a[2], a[3], 0, 0, 0, 0 };
    s16x8 b8 = { b[0], b[1], b[2], b[3], 0, 0, 0, 0 };
    return __builtin_amdgcn_mfma_f32_16x16x32_bf16(a8, b8, c, 0, 0, 0);
#endif
}

// ---------------------------------------------------------------------------
// Kernel 1: x transpose+convert: x fp32 [b][d][n] -> xT hi/lo bf16 [b][n][d].
// ---------------------------------------------------------------------------
__global__ __launch_bounds__(256) void xt_kernel(
    const float* __restrict__ x, unsigned short* __restrict__ xthi,
    unsigned short* __restrict__ xtlo)
{
    __shared__ float tile[64 * 68];
    int t = threadIdx.x;
    int b = blockIdx.z, d0 = blockIdx.y * 64, n0 = blockIdx.x * 64;
    int dl = t >> 4, n4 = (t & 15) * 4;
    #pragma unroll
    for (int i = 0; i < 4; ++i) {
        int d = dl + i * 16;
        float4 v = *(const float4*)(x + ((size_t)b * DDIM + d0 + d) * NSEQ + n0 + n4);
        *(float4*)(tile + d * 68 + n4) = v;
    }
    __syncthreads();
    int nl = t >> 2, dq = (t & 3) * 16;
    size_t base = ((size_t)b * NSEQ + n0 + nl) * DDIM + d0 + dq;
    #pragma unroll
    for (int g = 0; g < 4; ++g) {
        ushort4 hv, lv;
        #pragma unroll
        for (int k = 0; k < 4; ++k) {
            float v = tile[(dq + g * 4 + k) * 68 + nl];
            unsigned short hi = f2bf(v);
            ((unsigned short*)&hv)[k] = hi;
            ((unsigned short*)&lv)[k] = f2bf(v - bf2f(hi));
        }
        *(ushort4*)(xthi + base + g * 4) = hv;
        *(ushort4*)(xtlo + base + g * 4) = lv;
    }
}

// ---------------------------------------------------------------------------
// Kernel 2: weight convert: qp (0.125 folded) and op -> hi/lo bf16.
// ---------------------------------------------------------------------------
__global__ __launch_bounds__(256) void wconv_kernel(
    const float* __restrict__ qp, const float* __restrict__ op,
    unsigned short* __restrict__ qphi, unsigned short* __restrict__ qplo,
    unsigned short* __restrict__ ophi, unsigned short* __restrict__ oplo)
{
    int e = (blockIdx.x * 256 + threadIdx.x) * 4;
    const float* src = blockIdx.y ? op : qp;
    unsigned short* dh = blockIdx.y ? ophi : qphi;
    unsigned short* dl = blockIdx.y ? oplo : qplo;
    float sc = blockIdx.y ? 1.0f : 0.125f;
    float4 v = *(const float4*)(src + e);
    v.x *= sc; v.y *= sc; v.z *= sc; v.w *= sc;
    ushort4 hv, lv;
    hv.x = f2bf(v.x); lv.x = f2bf(v.x - bf2f(hv.x));
    hv.y = f2bf(v.y); lv.y = f2bf(v.y - bf2f(hv.y));
    hv.z = f2bf(v.z); lv.z = f2bf(v.z - bf2f(hv.z));
    hv.w = f2bf(v.w); lv.w = f2bf(v.w - bf2f(hv.w));
    *(ushort4*)(dh + e) = hv;
    *(ushort4*)(dl + e) = lv;
}

// ---------------------------------------------------------------------------
// Kernel 3: K/V weight transpose+convert: kp/vp fp32 [d][64] -> [64 j][512 d]
// hi/lo bf16.
// ---------------------------------------------------------------------------
__global__ __launch_bounds__(256) void kvw_kernel(
    const float* __restrict__ kp, const float* __restrict__ vp,
    unsigned short* __restrict__ kpthi, unsigned short* __restrict__ kptlo,
    unsigned short* __restrict__ vpthi, unsigned short* __restrict__ vptlo)
{
    __shared__ float tile[64 * 68];
    int t = threadIdx.x;
    int d0 = blockIdx.x * 64;
    const float* src = blockIdx.y ? vp : kp;
    unsigned short* dsth = blockIdx.y ? vpthi : kpthi;
    unsigned short* dstl = blockIdx.y ? vptlo : kptlo;
    int dl = t >> 4, j4 = (t & 15) * 4;
    #pragma unroll
    for (int i = 0; i < 4; ++i) {
        int d = dl + i * 16;
        float4 v = *(const float4*)(src + (size_t)(d0 + d) * 64 + j4);
        *(float4*)(tile + d * 68 + j4) = v;
    }
    __syncthreads();
    int jl = t >> 2, dq = (t & 3) * 16;
    #pragma unroll
    for (int g = 0; g < 4; ++g) {
        ushort4 hv, lv;
        #pragma unroll
        for (int k = 0; k < 4; ++k) {
            float v = tile[(dq + g * 4 + k) * 68 + jl];
            unsigned short hi = f2bf(v);
            ((unsigned short*)&hv)[k] = hi;
            ((unsigned short*)&lv)[k] = f2bf(v - bf2f(hi));
        }
        *(ushort4*)(dsth + (size_t)jl * DDIM + d0 + dq + g * 4) = hv;
        *(ushort4*)(dstl + (size_t)jl * DDIM + d0 + dq + g * 4) = lv;
    }
}

// ---------------------------------------------------------------------------
// Kernel 4: K/V projection, MFMA. Unchanged from round 5.
// ---------------------------------------------------------------------------
__global__ __launch_bounds__(256, 2) void kv_proj_kernel(
    const unsigned short* __restrict__ xthi, const unsigned short* __restrict__ xtlo,
    const unsigned short* __restrict__ kpthi, const unsigned short* __restrict__ kptlo,
    const unsigned short* __restrict__ vpthi, const unsigned short* __restrict__ vptlo,
    unsigned short* __restrict__ kkhi, unsigned short* __restrict__ kklo,
    unsigned short* __restrict__ vthi, unsigned short* __restrict__ vtlo)
{
    __shared__ __align__(128) char arena[32768];
    const int tid = threadIdx.x;
    const int w = tid >> 6, l = tid & 63;
    const int qd = l >> 4, ln = l & 15;
    const int b = blockIdx.y;
    const int m0 = blockIdx.x * 64;

    const int vrow = l >> 3, gsw = (l & 7) ^ vrow;
    const int tsel = w >> 1;
    const int mhalf = (w & 1) * 32;
    const char* sxb = (const char*)(tsel ? xtlo : xthi)
        + ((size_t)(b * NSEQ + m0 + mhalf) * DDIM) * 2
        + (size_t)vrow * 1024 + (size_t)gsw * 16;
    char* dst0 = arena + tsel * 8192 + mhalf * 128;

    auto stage = [&](int buf, int s) {
        const char* gg = sxb + (size_t)s * 128;
        char* dd = dst0 + buf * 16384;
        #pragma unroll
        for (int i = 0; i < 4; ++i)
            __builtin_amdgcn_global_load_lds(
                (const __attribute__((address_space(1))) unsigned int*)(gg + (size_t)i * 8 * 1024),
                (__attribute__((address_space(3))) unsigned int*)(dd + i * 1024),
                16, 0, 0);
    };

    const int isV = w >> 1;
    const int jh  = w & 1;
    const unsigned short* wh = (isV ? vpthi : kpthi) + (size_t)(jh * 32) * DDIM;
    const unsigned short* wl = (isV ? vptlo : kptlo) + (size_t)(jh * 32) * DDIM;

    f32x4 acc[2][4];
    const f32x4 vzero = {0.f, 0.f, 0.f, 0.f};
    #pragma unroll
    for (int js = 0; js < 2; ++js)
        #pragma unroll
        for (int ms = 0; ms < 4; ++ms) acc[js][ms] = vzero;

    stage(0, 0);
    for (int s = 0; s < 8; ++s) {
        int buf = s & 1;
        __syncthreads();
        if (s + 1 < 8) stage(buf ^ 1, s + 1);
        const char* Bh = arena + buf * 16384;
        const char* Bl = Bh + 8192;
        #pragma unroll
        for (int hh = 0; hh < 2; ++hh) {
            s16x8 ah[2], al[2];
            #pragma unroll
            for (int js = 0; js < 2; ++js) {
                size_t ao = (size_t)(js * 16 + ln) * DDIM + s * 64 + hh * 32 + qd * 8;
                ah[js] = *(const s16x8*)(wh + ao);
                al[js] = *(const s16x8*)(wl + ao);
            }
            int goff = ((hh * 4 + qd) ^ (ln & 7)) * 16;
            #pragma unroll
            for (int ms = 0; ms < 4; ++ms) {
                int ro = (ms * 16 + ln) * 128 + goff;
                s16x8 bh = *(const s16x8*)(Bh + ro);
                s16x8 bl = *(const s16x8*)(Bl + ro);
                #pragma unroll
                for (int js = 0; js < 2; ++js) {
                    acc[js][ms] = mfma32(ah[js], bh, acc[js][ms]);
                    acc[js][ms] = mfma32(ah[js], bl, acc[js][ms]);
                    acc[js][ms] = mfma32(al[js], bh, acc[js][ms]);
                }
            }
        }
    }

    if (isV) {
        #pragma unroll
        for (int js = 0; js < 2; ++js)
            #pragma unroll
            for (int ms = 0; ms < 4; ++ms)
                #pragma unroll
                for (int r = 0; r < 4; ++r) {
                    int v = jh * 32 + js * 16 + qd * 4 + r;
                    size_t o = ((size_t)b * 64 + v) * NSEQ + m0 + ms * 16 + ln;
                    float val = acc[js][ms][r];
                    unsigned short hi = f2bf(val);
                    vthi[o] = hi;
                    vtlo[o] = f2bf(val - bf2f(hi));
                }
    }
    __syncthreads();
    float* eb = (float*)arena;
    if (!isV) {
        #pragma unroll
        for (int js = 0; js < 2; ++js)
            #pragma unroll
            for (int ms = 0; ms < 4; ++ms)
                #pragma unroll
                for (int r = 0; r < 4; ++r)
                    eb[(ms * 16 + ln) * 66 + jh * 32 + js * 16 + qd * 4 + r]
                        = acc[js][ms][r];
    }
    __syncthreads();
    {
        int m = tid >> 2, jg = (tid & 3) * 16;
        size_t base = ((size_t)b * NSEQ + m0 + m) * 64 + jg;
        #pragma unroll
        for (int g = 0; g < 4; ++g) {
            ushort4 hv, lv;
            #pragma unroll
            for (int k = 0; k < 4; ++k) {
                float v = eb[m * 66 + jg + g * 4 + k];
                unsigned short hi = f2bf(v);
                ((unsigned short*)&hv)[k] = hi;
                ((unsigned short*)&lv)[k] = f2bf(v - bf2f(hi));
            }
            *(ushort4*)(kkhi + base + g * 4) = hv;
            *(ushort4*)(kklo + base + g * 4) = lv;
        }
    }
}

// ---------------------------------------------------------------------------
// Kernel 5: Q projection, MFMA. Unchanged from round 4/5.
// ---------------------------------------------------------------------------
__global__ __launch_bounds__(256, 2) void q_proj_kernel(
    const unsigned short* __restrict__ xthi, const unsigned short* __restrict__ xtlo,
    const unsigned short* __restrict__ qphi, const unsigned short* __restrict__ qplo,
    unsigned short* __restrict__ qhi, unsigned short* __restrict__ qlo)
{
    __shared__ __align__(128) char arena[65536];
    const int tid = threadIdx.x;
    const int w = tid >> 6, l = tid & 63;
    const int qd = l >> 4, ln = l & 15;
    const int b = blockIdx.z, h = blockIdx.y;
    const int n0 = blockIdx.x * 128;

    const int vrow = l >> 3, gsw = (l & 7) ^ vrow;
    const int tsel = w >> 1;
    const int rhalf = (w & 1) * 64;
    const char* sb = (const char*)(tsel ? xtlo : xthi)
        + ((size_t)(b * NSEQ + n0 + rhalf) * DDIM) * 2
        + (size_t)vrow * 1024 + (size_t)gsw * 16;
    char* dst0 = arena + tsel * 16384 + rhalf * 128;

    auto stage = [&](int buf, int s) {
        const char* gg = sb + (size_t)s * 128;
        char* dd = dst0 + buf * 32768;
        #pragma unroll
        for (int i = 0; i < 8; ++i)
            __builtin_amdgcn_global_load_lds(
                (const __attribute__((address_space(1))) unsigned int*)(gg + (size_t)i * 8192),
                (__attribute__((address_space(3))) unsigned int*)(dd + i * 1024),
                16, 0, 0);
    };

    f32x4 acc[8];
    const f32x4 vzero = {0.f, 0.f, 0.f, 0.f};
    #pragma unroll
    for (int i = 0; i < 8; ++i) acc[i] = vzero;

    const unsigned short* qpb_h = qphi + ((size_t)h * 64 + w * 16 + ln) * DDIM;
    const unsigned short* qpb_l = qplo + ((size_t)h * 64 + w * 16 + ln) * DDIM;

    stage(0, 0);
    for (int s = 0; s < 8; ++s) {
        int buf = s & 1;
        __syncthreads();
        if (s + 1 < 8) stage(buf ^ 1, s + 1);
        const char* Bh = arena + buf * 32768;
        const char* Bl = Bh + 16384;
        #pragma unroll
        for (int hh = 0; hh < 2; ++hh) {
            s16x8 ah = *(const s16x8*)(qpb_h + s * 64 + hh * 32 + qd * 8);
            s16x8 al = *(const s16x8*)(qpb_l + s * 64 + hh * 32 + qd * 8);
            int goff = ((hh * 4 + qd) ^ (ln & 7)) * 16;
            #pragma unroll
            for (int ns = 0; ns < 8; ++ns) {
                int ro = (ns * 16 + ln) * 128 + goff;
                s16x8 bh = *(const s16x8*)(Bh + ro);
                s16x8 bl = *(const s16x8*)(Bl + ro);
                acc[ns] = mfma32(ah, bh, acc[ns]);
                acc[ns] = mfma32(ah, bl, acc[ns]);
                acc[ns] = mfma32(al, bh, acc[ns]);
            }
        }
    }
    __syncthreads();
    float* eb = (float*)arena;
    #pragma unroll
    for (int ns = 0; ns < 8; ++ns)
        #pragma unroll
        for (int r = 0; r < 4; ++r)
            eb[(ns * 16 + ln) * 69 + w * 16 + qd * 4 + r] = acc[ns][r];
    __syncthreads();
    {
        int n = tid >> 1, half = tid & 1;
        size_t base = (((size_t)b * NHEAD + h) * NSEQ + n0 + n) * 64 + half * 32;
        #pragma unroll
        for (int g = 0; g < 8; ++g) {
            ushort4 hv, lv;
            #pragma unroll
            for (int k = 0; k < 4; ++k) {
                float v = eb[n * 69 + half * 32 + g * 4 + k];
                unsigned short hi = f2bf(v);
                ((unsigned short*)&hv)[k] = hi;
                ((unsigned short*)&lv)[k] = f2bf(v - bf2f(hi));
            }
            *(ushort4*)(qhi + base + g * 4) = hv;
            *(ushort4*)(qlo + base + g * 4) = lv;
        }
    }
}

// ---------------------------------------------------------------------------
// Kernel 6: MFMA flash attention — ONLINE-MAX softmax core (round-5 verbatim;
// the only core with demonstrated post-timing stability across 3 passing
// rounds). Epilogue stores o as hi/lo bf16 pair (round-8 accuracy hedge).
// ---------------------------------------------------------------------------
__global__ __launch_bounds__(256, 2) void attn_kernel(
    const unsigned short* __restrict__ kkhi, const unsigned short* __restrict__ kklo,
    const unsigned short* __restrict__ vthi, const unsigned short* __restrict__ vtlo,
    const unsigned short* __restrict__ qhi,  const unsigned short* __restrict__ qlo,
    unsigned short* __restrict__ obfhi, unsigned short* __restrict__ obflo)
{
    __shared__ __align__(128) char arena[65536];

    const int tid = threadIdx.x;
    const int w  = tid >> 6;
    const int l  = tid & 63;
    const int qd = l >> 4;
    const int ln = l & 15;
    const int bz = blockIdx.z, hz = blockIdx.y;
    const int n0 = blockIdx.x * 64;

    s16x8 qh[4][2], qlo_[4][2];
    {
        size_t rowb = (((size_t)bz * NHEAD + hz) * NSEQ + n0 + ln) * 64 + qd * 8;
        #pragma unroll
        for (int t = 0; t < 4; ++t)
            #pragma unroll
            for (int c = 0; c < 2; ++c) {
                qh[t][c]   = *(const s16x8*)(qhi + rowb + (size_t)t * 16 * 64 + c * 32);
                qlo_[t][c] = *(const s16x8*)(qlo + rowb + (size_t)t * 16 * 64 + c * 32);
            }
    }

    const int vrow = l >> 3;
    const int gsw  = (l & 7) ^ vrow;
    const char* sb; int rs, ts;
    if      (w == 0) { sb = (const char*)kkhi; rs = 128;  ts = 8192; }
    else if (w == 1) { sb = (const char*)kklo; rs = 128;  ts = 8192; }
    else if (w == 2) { sb = (const char*)vthi; rs = 4096; ts = 128;  }
    else             { sb = (const char*)vtlo; rs = 4096; ts = 128;  }
    sb += (size_t)bz * 262144 + (size_t)vrow * rs + (size_t)gsw * 16;
    char* ldst0 = arena + w * 8192;

    auto stage = [&](int buf, int mt) {
        const char* gg = sb + (size_t)mt * ts;
        char* dst = ldst0 + buf * 32768;
        #pragma unroll
        for (int i = 0; i < 8; ++i) {
            __builtin_amdgcn_global_load_lds(
                (const __attribute__((address_space(1))) unsigned int*)(gg + (size_t)i * 8 * rs),
                (__attribute__((address_space(3))) unsigned int*)(dst + i * 1024),
                16, 0, 0);
        }
    };

    int offK[2], offV[4];
    #pragma unroll
    for (int c = 0; c < 2; ++c)
        offK[c] = (w * 16 + ln) * 128 + (((c * 4 + qd) ^ (ln & 7)) * 16);
    #pragma unroll
    for (int s = 0; s < 4; ++s)
        offV[s] = (s * 16 + ln) * 128 + (((2 * w + (qd >> 1)) ^ (ln & 7)) * 16) + (qd & 1) * 8;

    f32x4 O[4][4];
    const f32x4 vzero = {0.f, 0.f, 0.f, 0.f};
    #pragma unroll
    for (int s = 0; s < 4; ++s)
        #pragma unroll
        for (int t = 0; t < 4; ++t) O[s][t] = vzero;
    float mi[4], li[4];
    #pragma unroll
    for (int t = 0; t < 4; ++t) { mi[t] = -1e30f; li[t] = 0.f; }

    stage(0, 0);

    for (int mt = 0; mt < 32; ++mt) {
        int buf = mt & 1;
        __syncthreads();
        if (mt + 1 < 32) stage(buf ^ 1, mt + 1);
        const char* Kh = arena + buf * 32768;
        const char* Kl = Kh + 8192;
        const char* Vh = Kh + 16384;
        const char* Vl = Kh + 24576;

        s16x8 kh[2], kl[2];
        #pragma unroll
        for (int c = 0; c < 2; ++c) {
            kh[c] = *(const s16x8*)(Kh + offK[c]);
            kl[c] = *(const s16x8*)(Kl + offK[c]);
        }
        f32x4 S[4];
        #pragma unroll
        for (int t = 0; t < 4; ++t) S[t] = vzero;
        #pragma unroll
        for (int c = 0; c < 2; ++c)
            #pragma unroll
            for (int t = 0; t < 4; ++t) {
                S[t] = mfma32(kh[c], qh[t][c],   S[t]);
                S[t] = mfma32(kh[c], qlo_[t][c], S[t]);
                S[t] = mfma32(kl[c], qh[t][c],   S[t]);
            }

        // online softmax over this wave's 16 m's (round-5 core)
        s16x4 pb[4]; float corr[4];
        #pragma unroll
        for (int t = 0; t < 4; ++t) {
            float rmax = fmaxf(fmaxf(S[t][0], S[t][1]), fmaxf(S[t][2], S[t][3]));
            rmax = fmaxf(rmax, __shfl_xor(rmax, 16, 64));
            rmax = fmaxf(rmax, __shfl_xor(rmax, 32, 64));
            float mnew = fmaxf(mi[t], rmax);
            corr[t] = __expf(mi[t] - mnew);
            mi[t] = mnew;
            float p0 = __expf(S[t][0] - mnew);
            float p1 = __expf(S[t][1] - mnew);
            float p2 = __expf(S[t][2] - mnew);
            float p3 = __expf(S[t][3] - mnew);
            float ps = p0 + p1 + p2 + p3;
            ps += __shfl_xor(ps, 16, 64);
            ps += __shfl_xor(ps, 32, 64);
            li[t] = li[t] * corr[t] + ps;
            pb[t] = pack4(p0, p1, p2, p3);
        }
        #pragma unroll
        for (int s = 0; s < 4; ++s)
            #pragma unroll
            for (int t = 0; t < 4; ++t)
                O[s][t] *= corr[t];
        #pragma unroll
        for (int s = 0; s < 4; ++s) {
            s16x4 vh = *(const s16x4*)(Vh + offV[s]);
            s16x4 vl = *(const s16x4*)(Vl + offV[s]);
            #pragma unroll
            for (int t = 0; t < 4; ++t) {
                O[s][t] = mfma16(vh, pb[t], O[s][t]);
                O[s][t] = mfma16(vl, pb[t], O[s][t]);
            }
        }
    }

    float* obuf  = (float*)arena;                 // [64 v][17] one n-subtile
    float* mlm   = (float*)(arena + 4608);        // [4 w][64 n]
    float* mll   = (float*)(arena + 5632);
    float* linvs = (float*)(arena + 6656);        // [64 n]

    if (qd == 0) {
        #pragma unroll
        for (int t = 0; t < 4; ++t) {
            mlm[w * 64 + t * 16 + ln] = mi[t];
            mll[w * 64 + t * 16 + ln] = li[t];
        }
    }
    __syncthreads();
    float f[4];
    #pragma unroll
    for (int t = 0; t < 4; ++t) {
        float M = mlm[t * 16 + ln];
        M = fmaxf(M, mlm[64 + t * 16 + ln]);
        M = fmaxf(M, mlm[128 + t * 16 + ln]);
        M = fmaxf(M, mlm[192 + t * 16 + ln]);
        float L = 0.f;
        #pragma unroll
        for (int ww = 0; ww < 4; ++ww)
            L += mll[ww * 64 + t * 16 + ln] * __expf(mlm[ww * 64 + t * 16 + ln] - M);
        f[t] = __expf(mi[t] - M);
        if (w == 0 && qd == 0) linvs[t * 16 + ln] = 1.0f / L;
    }

    #pragma unroll
    for (int t = 0; t < 4; ++t) {
        #pragma unroll
        for (int r = 0; r < 4; ++r) {
            __syncthreads();
            #pragma unroll
            for (int s = 0; s < 4; ++s) {
                if (((w + r) & 3) == s) {
                    f32x4 val = O[s][t] * f[t];
                    float* dst = obuf + (s * 16 + qd * 4) * 17 + ln;
                    if (r == 0) {
                        dst[0]  = val[0]; dst[17] = val[1];
                        dst[34] = val[2]; dst[51] = val[3];
                    } else {
                        dst[0]  += val[0]; dst[17] += val[1];
                        dst[34] += val[2]; dst[51] += val[3];
                    }
                }
            }
        }
        __syncthreads();
        int vq = tid & 15, nl = tid >> 4;
        float il = linvs[t * 16 + nl];
        ushort4 u4h, u4l;
        #pragma unroll
        for (int k = 0; k < 4; ++k) {
            float val = obuf[(vq * 4 + k) * 17 + nl] * il;
            unsigned short hi = f2bf(val);
            ((unsigned short*)&u4h)[k] = hi;
            ((unsigned short*)&u4l)[k] = f2bf(val - bf2f(hi));
        }
        size_t off = (((size_t)bz * NSEQ + n0 + t * 16 + nl) * 512) + hz * 64 + vq * 4;
        *(ushort4*)(obfhi + off) = u4h;
        *(ushort4*)(obflo + off) = u4l;
    }
}

// ---------------------------------------------------------------------------
// Kernel 7: output projection, MFMA, 3-pass hi/lo:
// out = op_hi·o_hi + op_hi·o_lo + op_lo·o_hi.
// ---------------------------------------------------------------------------
__global__ __launch_bounds__(256, 2) void out_proj_kernel(
    const unsigned short* __restrict__ obfhi, const unsigned short* __restrict__ obflo,
    const unsigned short* __restrict__ ophi, const unsigned short* __restrict__ oplo,
    float* __restrict__ out)
{
    __shared__ __align__(128) char arena[65536];  // dbuf x (hi 16K | lo 16K)
    const int tid = threadIdx.x;
    const int w = tid >> 6, l = tid & 63;
    const int qd = l >> 4, ln = l & 15;
    const int b = blockIdx.z, d0 = blockIdx.y * 64;
    const int n0 = blockIdx.x * 128;
    const int vrow = l >> 3, gsw = (l & 7) ^ vrow;

    const int tsel = w >> 1;              // 0: o-hi tensor, 1: o-lo tensor
    const int rhalf = (w & 1) * 64;       // n-half
    const char* sb = (const char*)(tsel ? obflo : obfhi)
        + ((size_t)(b * NSEQ + n0 + rhalf) * 512) * 2
        + (size_t)vrow * 1024 + (size_t)gsw * 16;
    char* dst0 = arena + tsel * 16384 + rhalf * 128;

    auto stage = [&](int buf, int s) {
        const char* gg = sb + (size_t)s * 128;
        char* dd = dst0 + buf * 32768;
        #pragma unroll
        for (int i = 0; i < 8; ++i)
            __builtin_amdgcn_global_load_lds(
                (const __attribute__((address_space(1))) unsigned int*)(gg + (size_t)i * 8192),
                (__attribute__((address_space(3))) unsigned int*)(dd + i * 1024),
                16, 0, 0);
    };

    f32x4 acc[8];
    const f32x4 vzero = {0.f, 0.f, 0.f, 0.f};
    #pragma unroll
    for (int i = 0; i < 8; ++i) acc[i] = vzero;

    const unsigned short* oph = ophi + (size_t)(d0 + w * 16 + ln) * 512;
    const unsigned short* opl = oplo + (size_t)(d0 + w * 16 + ln) * 512;

    stage(0, 0);
    for (int s = 0; s < 8; ++s) {
        int buf = s & 1;
        __syncthreads();
        if (s + 1 < 8) stage(buf ^ 1, s + 1);
        const char* Bh = arena + buf * 32768;
        const char* Bl = Bh + 16384;
        #pragma unroll
        for (int hh = 0; hh < 2; ++hh) {
            s16x8 ah = *(const s16x8*)(oph + s * 64 + hh * 32 + qd * 8);
            s16x8 al = *(const s16x8*)(opl + s * 64 + hh * 32 + qd * 8);
            int goff = ((hh * 4 + qd) ^ (ln & 7)) * 16;
            #pragma unroll
            for (int ns = 0; ns < 8; ++ns) {
                int ro = (ns * 16 + ln) * 128 + goff;
                s16x8 bh = *(const s16x8*)(Bh + ro);
                s16x8 bl = *(const s16x8*)(Bl + ro);
                acc[ns] = mfma32(ah, bh, acc[ns]);
                acc[ns] = mfma32(ah, bl, acc[ns]);
                acc[ns] = mfma32(al, bh, acc[ns]);
            }
        }
    }
    #pragma unroll
    for (int ns = 0; ns < 8; ++ns)
        #pragma unroll
        for (int r = 0; r < 4; ++r)
            out[((size_t)b * DDIM + d0 + w * 16 + qd * 4 + r) * NSEQ
                + n0 + ns * 16 + ln] = acc[ns][r];
}

// ---------------------------------------------------------------------------
extern "C" void kernel_launch(void* const* d_in, const int* in_sizes, int n_in,
                              void* d_out, int out_size, void* d_ws, size_t ws_size,
                              hipStream_t stream) {
    const float* x  = (const float*)d_in[0];   // (2,512,2048)
    const float* qp = (const float*)d_in[1];   // (8,64,512)
    const float* kp = (const float*)d_in[2];   // (512,64)
    const float* vp = (const float*)d_in[3];   // (512,64)
    const float* op = (const float*)d_in[4];   // (512,8,64)
    float* out = (float*)d_out;                // (2,512,2048)

    unsigned short* ws    = (unsigned short*)d_ws;
    unsigned short* kkhi  = ws;                   // 262144
    unsigned short* kklo  = kkhi + 262144;
    unsigned short* vthi  = kklo + 262144;
    unsigned short* vtlo  = vthi + 262144;
    unsigned short* qphi  = vtlo + 262144;
    unsigned short* qplo  = qphi + 262144;
    unsigned short* ophi  = qplo + 262144;
    unsigned short* oplo  = ophi + 262144;
    unsigned short* kpthi = oplo + 262144;        // 32768
    unsigned short* kptlo = kpthi + 32768;
    unsigned short* vpthi = kptlo + 32768;
    unsigned short* vptlo = vpthi + 32768;
    unsigned short* xthi  = vptlo + 32768;        // 2097152
    unsigned short* xtlo  = xthi + 2097152;
    unsigned short* qhi   = xtlo + 2097152;
    unsigned short* qlo   = qhi + 2097152;
    unsigned short* obfhi = xthi;                 // alias (xT dead after projs)
    unsigned short* obflo = xtlo;                 // alias

    hipLaunchKernelGGL(xt_kernel,       dim3(32, 8, 2),  dim3(256), 0, stream,
                       x, xthi, xtlo);
    hipLaunchKernelGGL(wconv_kernel,    dim3(256, 2),    dim3(256), 0, stream,
                       qp, op, qphi, qplo, ophi, oplo);
    hipLaunchKernelGGL(kvw_kernel,      dim3(8, 2),      dim3(256), 0, stream,
                       kp, vp, kpthi, kptlo, vpthi, vptlo);
    hipLaunchKernelGGL(kv_proj_kernel,  dim3(32, 2),     dim3(256), 0, stream,
                       xthi, xtlo, kpthi, kptlo, vpthi, vptlo,
                       kkhi, kklo, vthi, vtlo);
    hipLaunchKernelGGL(q_proj_kernel,   dim3(16, 8, 2),  dim3(256), 0, stream,
                       xthi, xtlo, qphi, qplo, qhi, qlo);
    hipLaunchKernelGGL(attn_kernel,     dim3(32, 8, 2),  dim3(256), 0, stream,
                       kkhi, kklo, vthi, vtlo, qhi, qlo, obfhi, obflo);
    hipLaunchKernelGGL(out_proj_kernel, dim3(16, 8, 2),  dim3(256), 0, stream,
                       obfhi, obflo, ophi, oplo, out);
}